// Round 1
// baseline (513.005 us; speedup 1.0000x reference)
//
#include <hip/hip_runtime.h>
#include <math.h>

#define BETA_C 0.85f   // 1 - alpha
#define ALF_C  0.15f   // alpha

// ---------------- preprocessing kernels ----------------

__global__ void k_init(int* __restrict__ cnt, int* __restrict__ cur, int n) {
    int i = blockIdx.x * blockDim.x + threadIdx.x;
    if (i < n) { cnt[i] = 0; cur[i] = 0; }
}

__global__ void k_count(const int* __restrict__ col, int* __restrict__ cnt, int E) {
    int stride = gridDim.x * blockDim.x;
    for (int e = blockIdx.x * blockDim.x + threadIdx.x; e < E; e += stride)
        atomicAdd(&cnt[col[e]], 1);
}

__global__ void k_dinv(const int* __restrict__ cnt, float* __restrict__ dinv, int n) {
    int i = blockIdx.x * blockDim.x + threadIdx.x;
    if (i < n) dinv[i] = rsqrtf((float)cnt[i] + 1.0f);  // +1 self-loop; deg>=1 always
}

// 3-pass exclusive scan of cnt[0..n) -> offs, offs[n]=total
__global__ void k_scan1(const int* __restrict__ cnt, int* __restrict__ aux, int n) {
    __shared__ int sm[4];
    int t = threadIdx.x;
    int base = blockIdx.x * 1024 + t * 4;
    int s = 0;
#pragma unroll
    for (int i = 0; i < 4; ++i) { int idx = base + i; if (idx < n) s += cnt[idx]; }
    for (int m = 1; m < 64; m <<= 1) s += __shfl_xor(s, m, 64);
    if ((t & 63) == 0) sm[t >> 6] = s;
    __syncthreads();
    if (t == 0) aux[blockIdx.x] = sm[0] + sm[1] + sm[2] + sm[3];
}

__global__ void k_scan2(int* __restrict__ aux, int nb) {
    if (threadIdx.x == 0 && blockIdx.x == 0) {
        int run = 0;
        for (int i = 0; i < nb; ++i) { int v = aux[i]; aux[i] = run; run += v; }
    }
}

__global__ void k_scan3(const int* __restrict__ cnt, const int* __restrict__ aux,
                        int* __restrict__ offs, int n, int total) {
    __shared__ int tsum[256];
    int t = threadIdx.x;
    int base = blockIdx.x * 1024 + t * 4;
    int v[4]; int s = 0;
#pragma unroll
    for (int i = 0; i < 4; ++i) { v[i] = (base + i < n) ? cnt[base + i] : 0; s += v[i]; }
    tsum[t] = s;
    __syncthreads();
    int run = s;
    for (int m = 1; m < 256; m <<= 1) {
        int add = (t >= m) ? tsum[t - m] : 0;
        __syncthreads();
        run += add;
        tsum[t] = run;
        __syncthreads();
    }
    int pre = aux[blockIdx.x] + (run - s);   // exclusive prefix for this thread's 4 elems
#pragma unroll
    for (int i = 0; i < 4; ++i) {
        int idx = base + i;
        if (idx < n) { offs[idx] = pre; pre += v[i]; }
    }
    if (blockIdx.x == 0 && t == 0) offs[n] = total;
}

__global__ void k_fill(const int* __restrict__ row, const int* __restrict__ col,
                       const int* __restrict__ offs, int* __restrict__ cur,
                       const float* __restrict__ dinv,
                       int* __restrict__ adj, float* __restrict__ wgt, int E) {
    int stride = gridDim.x * blockDim.x;
    for (int e = blockIdx.x * blockDim.x + threadIdx.x; e < E; e += stride) {
        int c = col[e], r = row[e];
        int p = atomicAdd(&cur[c], 1);
        int o = offs[c] + p;
        adj[o] = r;
        wgt[o] = BETA_C * dinv[r] * dinv[c];  // fold 0.85 into edge weight
    }
}

// ---------------- GEMM + bias + row-L2-norm*scale ----------------
// H[n,FO] = l2norm(X[n,FI] @ W[FI,FO] + b) * scale
template<int FI, int FO>
__global__ __launch_bounds__(256) void k_gemm_norm(
        const float* __restrict__ X, const float* __restrict__ W,
        const float* __restrict__ B, float* __restrict__ H, int n, float scale) {
    constexpr int BM = 64, BK = 32;
    constexpr int TN = FO / 16;           // 6 (FO=96) or 4 (FO=64)
    __shared__ float As[BK][BM + 1];      // transposed A tile, padded
    __shared__ float Bs[BK][FO];
    int tid = threadIdx.x;
    int rb = blockIdx.x * BM;
    int tcol = tid & 15, trow = tid >> 4;
    float acc[4][TN];
#pragma unroll
    for (int i = 0; i < 4; ++i)
#pragma unroll
        for (int t = 0; t < TN; ++t) acc[i][t] = 0.f;

    for (int kb = 0; kb < FI; kb += BK) {
        // A tile: 64 rows x 32 cols = 512 float4, 2 per thread
#pragma unroll
        for (int ld = 0; ld < 2; ++ld) {
            int idx = tid + ld * 256;
            int r = idx >> 3, c4 = idx & 7;
            float4 v = make_float4(0.f, 0.f, 0.f, 0.f);
            int gr = rb + r;
            if (gr < n) v = *reinterpret_cast<const float4*>(X + (size_t)gr * FI + kb + c4 * 4);
            As[c4 * 4 + 0][r] = v.x; As[c4 * 4 + 1][r] = v.y;
            As[c4 * 4 + 2][r] = v.z; As[c4 * 4 + 3][r] = v.w;
        }
        // B tile: BK x FO floats
        constexpr int NB4 = BK * FO / 4;
#pragma unroll
        for (int idx = tid; idx < NB4; idx += 256) {
            int k = idx / (FO / 4), c4 = idx % (FO / 4);
            float4 v = *reinterpret_cast<const float4*>(W + (size_t)(kb + k) * FO + c4 * 4);
            *reinterpret_cast<float4*>(&Bs[k][c4 * 4]) = v;
        }
        __syncthreads();
#pragma unroll
        for (int k = 0; k < BK; ++k) {
            float a[4];
#pragma unroll
            for (int i = 0; i < 4; ++i) a[i] = As[k][trow * 4 + i];
            float b[TN];
#pragma unroll
            for (int t = 0; t < TN; ++t) b[t] = Bs[k][tcol * TN + t];
#pragma unroll
            for (int i = 0; i < 4; ++i)
#pragma unroll
                for (int t = 0; t < TN; ++t) acc[i][t] += a[i] * b[t];
        }
        __syncthreads();
    }
    // bias + row sumsq
    float bv[TN];
#pragma unroll
    for (int t = 0; t < TN; ++t) bv[t] = B[tcol * TN + t];
    float ss[4];
#pragma unroll
    for (int i = 0; i < 4; ++i) {
        float s = 0.f;
#pragma unroll
        for (int t = 0; t < TN; ++t) { acc[i][t] += bv[t]; s += acc[i][t] * acc[i][t]; }
        ss[i] = s;
    }
    // reduce across the 16 lanes sharing a row group (lanes trow*16..+15)
    for (int m = 1; m < 16; m <<= 1) {
#pragma unroll
        for (int i = 0; i < 4; ++i) ss[i] += __shfl_xor(ss[i], m, 64);
    }
#pragma unroll
    for (int i = 0; i < 4; ++i) {
        int gr = rb + trow * 4 + i;
        if (gr < n) {
            float sc = scale / fmaxf(sqrtf(ss[i]), 1e-12f);
#pragma unroll
            for (int t = 0; t < TN; ++t)
                H[(size_t)gr * FO + tcol * TN + t] = acc[i][t] * sc;
        }
    }
}

// ---------------- APPNP propagation step (CSR gather) ----------------
// out[c] = 0.85*dinv[c]^2*in[c] + sum_nb wgt*in[r] + 0.15*h[c]   (+optional relu)
template<int FO4, int NPB, int ACT>
__global__ void k_prop(const float4* __restrict__ in, const float4* __restrict__ h,
                       float4* __restrict__ out, const int* __restrict__ offs,
                       const int* __restrict__ adj, const float* __restrict__ wgt,
                       const float* __restrict__ dinv, int n) {
    int tid = threadIdx.x;
    int cl = tid / FO4, j = tid % FO4;
    int c = blockIdx.x * NPB + cl;
    if (c >= n) return;
    float dv = dinv[c];
    float selfw = BETA_C * dv * dv;
    float4 xc = in[(size_t)c * FO4 + j];
    float4 acc;
    acc.x = selfw * xc.x; acc.y = selfw * xc.y;
    acc.z = selfw * xc.z; acc.w = selfw * xc.w;
    int e = offs[c], end = offs[c + 1];
    for (; e < end; ++e) {
        int r = adj[e];
        float w = wgt[e];
        float4 v = in[(size_t)r * FO4 + j];
        acc.x += w * v.x; acc.y += w * v.y; acc.z += w * v.z; acc.w += w * v.w;
    }
    float4 hv = h[(size_t)c * FO4 + j];
    float4 res;
    res.x = acc.x + ALF_C * hv.x; res.y = acc.y + ALF_C * hv.y;
    res.z = acc.z + ALF_C * hv.z; res.w = acc.w + ALF_C * hv.w;
    if (ACT == 1) {
        res.x = fmaxf(res.x, 0.f); res.y = fmaxf(res.y, 0.f);
        res.z = fmaxf(res.z, 0.f); res.w = fmaxf(res.w, 0.f);
    }
    out[(size_t)c * FO4 + j] = res;
}

// ---------------- standalone row l2norm * scale (in-place, FO=96) ----------------
__global__ void k_l2norm96(float* __restrict__ x, int n, float scale) {
    int lane = threadIdx.x & 63, wave = threadIdx.x >> 6;
    int r = blockIdx.x * 4 + wave;
    if (r >= n) return;
    float* p = x + (size_t)r * 96;
    float v0 = p[lane];
    float v1 = (lane < 32) ? p[64 + lane] : 0.f;
    float ss = v0 * v0 + v1 * v1;
    for (int m = 1; m < 64; m <<= 1) ss += __shfl_xor(ss, m, 64);
    float sc = scale / fmaxf(sqrtf(ss), 1e-12f);
    p[lane] = v0 * sc;
    if (lane < 32) p[64 + lane] = v1 * sc;
}

// ---------------- host launcher ----------------
extern "C" void kernel_launch(void* const* d_in, const int* in_sizes, int n_in,
                              void* d_out, int out_size, void* d_ws, size_t ws_size,
                              hipStream_t stream) {
    const float* x  = (const float*)d_in[0];
    const int*   ei = (const int*)d_in[1];
    const float* W0 = (const float*)d_in[2];
    const float* b0 = (const float*)d_in[3];
    const float* W1 = (const float*)d_in[4];
    const float* b1 = (const float*)d_in[5];
    const float* Wx = (const float*)d_in[6];
    const float* bx = (const float*)d_in[7];
    float* out = (float*)d_out;

    const int N = in_sizes[0] / 256;
    const int E = in_sizes[1] / 2;
    const int* row = ei;
    const int* col = ei + E;

    char* ws = (char*)d_ws;
    size_t off = 0;
    auto alloc = [&](size_t bytes) -> char* {
        char* p = ws + off;
        off += (bytes + 255) & ~(size_t)255;
        return p;
    };
    int*   cnt  = (int*)alloc((size_t)N * 4);
    int*   cur  = (int*)alloc((size_t)N * 4);
    float* dinv = (float*)alloc((size_t)N * 4);
    int*   offs = (int*)alloc((size_t)(N + 1) * 4);
    int*   aux  = (int*)alloc(256 * 4);
    int*   adj  = (int*)alloc((size_t)E * 4);
    float* wgt  = (float*)alloc((size_t)E * 4);
    float* H    = (float*)alloc((size_t)N * 96 * 4);
    float* T1   = (float*)alloc((size_t)N * 96 * 4);
    float* T2   = (float*)alloc((size_t)N * 96 * 4);
    (void)ws_size; (void)n_in; (void)out_size;

    int nblkN = (N + 255) / 256;
    int nscan = (N + 1023) / 1024;
    k_init<<<nblkN, 256, 0, stream>>>(cnt, cur, N);
    k_count<<<1024, 256, 0, stream>>>(col, cnt, E);
    k_dinv<<<nblkN, 256, 0, stream>>>(cnt, dinv, N);
    k_scan1<<<nscan, 256, 0, stream>>>(cnt, aux, N);
    k_scan2<<<1, 64, 0, stream>>>(aux, nscan);
    k_scan3<<<nscan, 256, 0, stream>>>(cnt, aux, offs, N, E);
    k_fill<<<1024, 256, 0, stream>>>(row, col, offs, cur, dinv, adj, wgt, E);

    int gblk = (N + 63) / 64;
    // Layer 0: 256 -> 96, then APPNP, then relu (fused into 2nd prop)
    k_gemm_norm<256, 96><<<gblk, 256, 0, stream>>>(x, W0, b0, H, N, 1.8f);
    k_prop<24, 8, 0><<<(N + 7) / 8, 192, 0, stream>>>(
        (const float4*)H, (const float4*)H, (float4*)T1, offs, adj, wgt, dinv, N);
    k_prop<24, 8, 1><<<(N + 7) / 8, 192, 0, stream>>>(
        (const float4*)T1, (const float4*)H, (float4*)T2, offs, adj, wgt, dinv, N);

    // Layer 1: 96 -> 96, APPNP, then l2norm*1.5
    k_gemm_norm<96, 96><<<gblk, 256, 0, stream>>>(T2, W1, b1, H, N, 1.8f);
    k_prop<24, 8, 0><<<(N + 7) / 8, 192, 0, stream>>>(
        (const float4*)H, (const float4*)H, (float4*)T1, offs, adj, wgt, dinv, N);
    k_prop<24, 8, 0><<<(N + 7) / 8, 192, 0, stream>>>(
        (const float4*)T1, (const float4*)H, (float4*)T2, offs, adj, wgt, dinv, N);
    k_l2norm96<<<(N + 3) / 4, 256, 0, stream>>>(T2, N, 1.5f);

    // Layer 2: 96 -> 64, APPNP, output
    k_gemm_norm<96, 64><<<gblk, 256, 0, stream>>>(T2, Wx, bx, H, N, 1.8f);
    k_prop<16, 16, 0><<<(N + 15) / 16, 256, 0, stream>>>(
        (const float4*)H, (const float4*)H, (float4*)T1, offs, adj, wgt, dinv, N);
    k_prop<16, 16, 0><<<(N + 15) / 16, 256, 0, stream>>>(
        (const float4*)T1, (const float4*)H, (float4*)out, offs, adj, wgt, dinv, N);
}

// Round 2
// 347.213 us; speedup vs baseline: 1.4775x; 1.4775x over previous
//
#include <hip/hip_runtime.h>
#include <hip/hip_fp16.h>
#include <math.h>

#define BETA_C 0.85f   // 1 - alpha
#define ALF_C  0.15f   // alpha

typedef _Float16 f16x8 __attribute__((ext_vector_type(8)));
typedef float f32x4 __attribute__((ext_vector_type(4)));

// ---------------- preprocessing kernels ----------------

__global__ void k_init(int* __restrict__ cnt, int* __restrict__ cur, int n) {
    int i = blockIdx.x * blockDim.x + threadIdx.x;
    if (i < n) { cnt[i] = 0; cur[i] = 0; }
}

__global__ void k_count(const int* __restrict__ col, int* __restrict__ cnt, int E) {
    int stride = gridDim.x * blockDim.x;
    for (int e = blockIdx.x * blockDim.x + threadIdx.x; e < E; e += stride)
        atomicAdd(&cnt[col[e]], 1);
}

__global__ void k_dinv(const int* __restrict__ cnt, float* __restrict__ dinv, int n) {
    int i = blockIdx.x * blockDim.x + threadIdx.x;
    if (i < n) dinv[i] = rsqrtf((float)cnt[i] + 1.0f);  // +1 self-loop
}

__global__ void k_scan1(const int* __restrict__ cnt, int* __restrict__ aux, int n) {
    __shared__ int sm[4];
    int t = threadIdx.x;
    int base = blockIdx.x * 1024 + t * 4;
    int s = 0;
#pragma unroll
    for (int i = 0; i < 4; ++i) { int idx = base + i; if (idx < n) s += cnt[idx]; }
    for (int m = 1; m < 64; m <<= 1) s += __shfl_xor(s, m, 64);
    if ((t & 63) == 0) sm[t >> 6] = s;
    __syncthreads();
    if (t == 0) aux[blockIdx.x] = sm[0] + sm[1] + sm[2] + sm[3];
}

__global__ void k_scan2(int* __restrict__ aux, int nb) {
    if (threadIdx.x == 0 && blockIdx.x == 0) {
        int run = 0;
        for (int i = 0; i < nb; ++i) { int v = aux[i]; aux[i] = run; run += v; }
    }
}

__global__ void k_scan3(const int* __restrict__ cnt, const int* __restrict__ aux,
                        int* __restrict__ offs, int n, int total) {
    __shared__ int tsum[256];
    int t = threadIdx.x;
    int base = blockIdx.x * 1024 + t * 4;
    int v[4]; int s = 0;
#pragma unroll
    for (int i = 0; i < 4; ++i) { v[i] = (base + i < n) ? cnt[base + i] : 0; s += v[i]; }
    tsum[t] = s;
    __syncthreads();
    int run = s;
    for (int m = 1; m < 256; m <<= 1) {
        int add = (t >= m) ? tsum[t - m] : 0;
        __syncthreads();
        run += add;
        tsum[t] = run;
        __syncthreads();
    }
    int pre = aux[blockIdx.x] + (run - s);
#pragma unroll
    for (int i = 0; i < 4; ++i) {
        int idx = base + i;
        if (idx < n) { offs[idx] = pre; pre += v[i]; }
    }
    if (blockIdx.x == 0 && t == 0) offs[n] = total;
}

__global__ void k_fill(const int* __restrict__ row, const int* __restrict__ col,
                       const int* __restrict__ offs, int* __restrict__ cur,
                       const float* __restrict__ dinv,
                       int2* __restrict__ adjw, int E) {
    int stride = gridDim.x * blockDim.x;
    for (int e = blockIdx.x * blockDim.x + threadIdx.x; e < E; e += stride) {
        int c = col[e], r = row[e];
        int p = atomicAdd(&cur[c], 1);
        int o = offs[c] + p;
        float w = BETA_C * dinv[r] * dinv[c];
        adjw[o] = make_int2(r, __float_as_int(w));
    }
}

// W[FI][FO] fp32 -> WT[FO][FI] fp16
__global__ void k_prepw(const float* __restrict__ W, ushort* __restrict__ WT,
                        int FI, int FO) {
    int idx = blockIdx.x * blockDim.x + threadIdx.x;
    if (idx >= FI * FO) return;
    int nrow = idx / FI, k = idx % FI;
    _Float16 hv = (_Float16)W[(size_t)k * FO + nrow];
    WT[idx] = *(ushort*)&hv;
}

// ---------------- MFMA fp16 GEMM + bias + row-L2-norm*scale -> fp16 out -------
// H[n,FO] = fp16( l2norm(X[n,FI] @ W[FI,FO] + b) * scale )
// ASRC_F16: 0 = X fp32, 1 = X fp16
template<int FI, int FO, int ASRC_F16>
__global__ __launch_bounds__(256) void k_gemm_mfma(
        const void* __restrict__ Xv, const ushort* __restrict__ WT,
        const float* __restrict__ Bias, ushort* __restrict__ H, int n, float scale) {
    constexpr int NT = FO / 16;      // 16-wide n-tiles per wave
    constexpr int CPR = FI / 8;      // 16B chunks per row
    __shared__ ushort sA[64 * FI];
    __shared__ ushort sW[FO * FI];
    const int tid = threadIdx.x;
    const int rb = blockIdx.x * 64;

    // stage W^T (FO x FI halves), XOR-swizzled
    {
        constexpr int TOT = FO * CPR;
#pragma unroll
        for (int idx = tid; idx < TOT; idx += 256) {
            int nrow = idx / CPR, c = idx % CPR;
            uint4 v = *(((const uint4*)WT) + (size_t)nrow * CPR + c);
            int byte = ((nrow * FI + c * 8) * 2) ^ ((nrow & 7) << 4);
            *(uint4*)((char*)sW + byte) = v;
        }
    }
    // stage A (64 x FI halves), converting if needed, XOR-swizzled
    {
        constexpr int TOT = 64 * CPR;
#pragma unroll
        for (int idx = tid; idx < TOT; idx += 256) {
            int r = idx / CPR, c = idx % CPR;
            int gr = rb + r;
            uint4 v = make_uint4(0u, 0u, 0u, 0u);
            if (ASRC_F16) {
                if (gr < n) v = *(((const uint4*)Xv) + (size_t)gr * CPR + c);
            } else {
                if (gr < n) {
                    const float4* Xp = (const float4*)Xv;
                    float4 f0 = Xp[(size_t)gr * (FI / 4) + c * 2];
                    float4 f1 = Xp[(size_t)gr * (FI / 4) + c * 2 + 1];
                    _Float16 hv[8] = {(_Float16)f0.x, (_Float16)f0.y, (_Float16)f0.z,
                                      (_Float16)f0.w, (_Float16)f1.x, (_Float16)f1.y,
                                      (_Float16)f1.z, (_Float16)f1.w};
                    v = *(uint4*)hv;
                }
            }
            int byte = ((r * FI + c * 8) * 2) ^ ((r & 7) << 4);
            *(uint4*)((char*)sA + byte) = v;
        }
    }
    __syncthreads();

    const int lane = tid & 63;
    const int wave = tid >> 6;
    const int lcol = lane & 15;   // A row within wave tile / output col within n-tile
    const int lk = lane >> 4;     // k-subgroup

    f32x4 acc[NT];
#pragma unroll
    for (int t = 0; t < NT; ++t) acc[t] = (f32x4){0.f, 0.f, 0.f, 0.f};

    const int arow = wave * 16 + lcol;
    char* sAb = (char*)sA;
    char* sWb = (char*)sW;
#pragma unroll
    for (int s = 0; s < FI / 32; ++s) {
        int abyte = ((arow * FI + s * 32 + lk * 8) * 2) ^ ((arow & 7) << 4);
        f16x8 af = *(f16x8*)(sAb + abyte);
#pragma unroll
        for (int t = 0; t < NT; ++t) {
            int nrow = t * 16 + lcol;
            int bbyte = ((nrow * FI + s * 32 + lk * 8) * 2) ^ ((nrow & 7) << 4);
            f16x8 bf = *(f16x8*)(sWb + bbyte);
            acc[t] = __builtin_amdgcn_mfma_f32_16x16x32_f16(af, bf, acc[t], 0, 0, 0);
        }
    }

    // epilogue: bias, row sumsq (row = lk*4 + r, col = t*16 + lcol), l2norm*scale
    float bv[NT];
#pragma unroll
    for (int t = 0; t < NT; ++t) bv[t] = Bias[t * 16 + lcol];
    float ss[4] = {0.f, 0.f, 0.f, 0.f};
#pragma unroll
    for (int t = 0; t < NT; ++t)
#pragma unroll
        for (int r = 0; r < 4; ++r) {
            acc[t][r] += bv[t];
            ss[r] += acc[t][r] * acc[t][r];
        }
    for (int m = 1; m < 16; m <<= 1) {
#pragma unroll
        for (int r = 0; r < 4; ++r) ss[r] += __shfl_xor(ss[r], m, 64);
    }
#pragma unroll
    for (int r = 0; r < 4; ++r) {
        int grow = rb + wave * 16 + lk * 4 + r;
        if (grow < n) {
            float sc = scale / fmaxf(sqrtf(ss[r]), 1e-12f);
#pragma unroll
            for (int t = 0; t < NT; ++t) {
                _Float16 hv = (_Float16)(acc[t][r] * sc);
                H[(size_t)grow * FO + t * 16 + lcol] = *(ushort*)&hv;
            }
        }
    }
}

// ---------------- APPNP propagation (CSR gather, fp16 storage) ----------------
__device__ inline void unpack8(uint4 v, float* f) {
    union { uint4 u; _Float16 h[8]; } U; U.u = v;
#pragma unroll
    for (int i = 0; i < 8; ++i) f[i] = (float)U.h[i];
}

template<int FO, int NPB, int ACT, int OUTF32>
__global__ void k_prop_h(const uint4* __restrict__ in, const uint4* __restrict__ h,
                         void* __restrict__ out, const int* __restrict__ offs,
                         const int2* __restrict__ adjw, const float* __restrict__ dinv,
                         int n) {
    constexpr int C8 = FO / 8;
    int tid = threadIdx.x;
    int j = tid % C8, cl = tid / C8;
    int c = blockIdx.x * NPB + cl;
    if (c >= n) return;
    float dv = dinv[c];
    float selfw = BETA_C * dv * dv;
    float xf[8], acc[8];
    unpack8(in[(size_t)c * C8 + j], xf);
#pragma unroll
    for (int i = 0; i < 8; ++i) acc[i] = selfw * xf[i];
    int e = offs[c], end = offs[c + 1];
    for (; e < end; ++e) {
        int2 aw = adjw[e];
        float w = __int_as_float(aw.y);
        float vf[8];
        unpack8(in[(size_t)aw.x * C8 + j], vf);
#pragma unroll
        for (int i = 0; i < 8; ++i) acc[i] += w * vf[i];
    }
    float hf[8];
    unpack8(h[(size_t)c * C8 + j], hf);
#pragma unroll
    for (int i = 0; i < 8; ++i) {
        acc[i] += ALF_C * hf[i];
        if (ACT) acc[i] = fmaxf(acc[i], 0.f);
    }
    if (OUTF32) {
        float4* op = (float4*)out;
        float4 a = make_float4(acc[0], acc[1], acc[2], acc[3]);
        float4 b = make_float4(acc[4], acc[5], acc[6], acc[7]);
        op[(size_t)c * (FO / 4) + j * 2] = a;
        op[(size_t)c * (FO / 4) + j * 2 + 1] = b;
    } else {
        _Float16 hv[8];
#pragma unroll
        for (int i = 0; i < 8; ++i) hv[i] = (_Float16)acc[i];
        ((uint4*)out)[(size_t)c * C8 + j] = *(uint4*)hv;
    }
}

// ---------------- row l2norm * scale, fp16 in-place, FO=96 ----------------
__global__ void k_l2norm_h96(uint* __restrict__ x, int n, float scale) {
    int lane = threadIdx.x & 63, wave = threadIdx.x >> 6;
    int r = blockIdx.x * 4 + wave;
    if (r >= n) return;
    uint* p = x + (size_t)r * 48;   // 48 half2 per row
    float2 vf = make_float2(0.f, 0.f);
    uint v = 0;
    if (lane < 48) {
        v = p[lane];
        union { uint u; _Float16 h[2]; } U; U.u = v;
        vf.x = (float)U.h[0]; vf.y = (float)U.h[1];
    }
    float ss = vf.x * vf.x + vf.y * vf.y;
    for (int m = 1; m < 64; m <<= 1) ss += __shfl_xor(ss, m, 64);
    float sc = scale / fmaxf(sqrtf(ss), 1e-12f);
    if (lane < 48) {
        union { uint u; _Float16 h[2]; } U;
        U.h[0] = (_Float16)(vf.x * sc); U.h[1] = (_Float16)(vf.y * sc);
        p[lane] = U.u;
    }
}

// ---------------- host launcher ----------------
extern "C" void kernel_launch(void* const* d_in, const int* in_sizes, int n_in,
                              void* d_out, int out_size, void* d_ws, size_t ws_size,
                              hipStream_t stream) {
    const float* x  = (const float*)d_in[0];
    const int*   ei = (const int*)d_in[1];
    const float* W0 = (const float*)d_in[2];
    const float* b0 = (const float*)d_in[3];
    const float* W1 = (const float*)d_in[4];
    const float* b1 = (const float*)d_in[5];
    const float* Wx = (const float*)d_in[6];
    const float* bx = (const float*)d_in[7];
    float* out = (float*)d_out;

    const int N = in_sizes[0] / 256;
    const int E = in_sizes[1] / 2;
    const int* row = ei;
    const int* col = ei + E;

    char* ws = (char*)d_ws;
    size_t off = 0;
    auto alloc = [&](size_t bytes) -> char* {
        char* p = ws + off;
        off += (bytes + 255) & ~(size_t)255;
        return p;
    };
    int*    cnt  = (int*)alloc((size_t)N * 4);
    int*    cur  = (int*)alloc((size_t)N * 4);
    float*  dinv = (float*)alloc((size_t)N * 4);
    int*    offs = (int*)alloc((size_t)(N + 1) * 4);
    int*    aux  = (int*)alloc(256 * 4);
    int2*   adjw = (int2*)alloc((size_t)E * 8);
    ushort* WT0  = (ushort*)alloc((size_t)96 * 256 * 2);
    ushort* WT1  = (ushort*)alloc((size_t)96 * 96 * 2);
    ushort* WTx  = (ushort*)alloc((size_t)64 * 96 * 2);
    ushort* Hh   = (ushort*)alloc((size_t)N * 96 * 2);
    ushort* T1h  = (ushort*)alloc((size_t)N * 96 * 2);
    ushort* T2h  = (ushort*)alloc((size_t)N * 96 * 2);
    (void)ws_size; (void)n_in; (void)out_size;

    int nblkN = (N + 255) / 256;
    int nscan = (N + 1023) / 1024;
    k_init<<<nblkN, 256, 0, stream>>>(cnt, cur, N);
    k_count<<<1024, 256, 0, stream>>>(col, cnt, E);
    k_dinv<<<nblkN, 256, 0, stream>>>(cnt, dinv, N);
    k_scan1<<<nscan, 256, 0, stream>>>(cnt, aux, N);
    k_scan2<<<1, 64, 0, stream>>>(aux, nscan);
    k_scan3<<<nscan, 256, 0, stream>>>(cnt, aux, offs, N, E);
    k_fill<<<1024, 256, 0, stream>>>(row, col, offs, cur, dinv, adjw, E);
    k_prepw<<<(96 * 256 + 255) / 256, 256, 0, stream>>>(W0, WT0, 256, 96);
    k_prepw<<<(96 * 96 + 255) / 256, 256, 0, stream>>>(W1, WT1, 96, 96);
    k_prepw<<<(64 * 96 + 255) / 256, 256, 0, stream>>>(Wx, WTx, 96, 64);

    int gblk = (N + 63) / 64;
    // Layer 0: 256 -> 96 (fp32 A), APPNP x2 (relu fused into 2nd)
    k_gemm_mfma<256, 96, 0><<<gblk, 256, 0, stream>>>(x, WT0, b0, Hh, N, 1.8f);
    k_prop_h<96, 16, 0, 0><<<(N + 15) / 16, 192, 0, stream>>>(
        (const uint4*)Hh, (const uint4*)Hh, T1h, offs, adjw, dinv, N);
    k_prop_h<96, 16, 1, 0><<<(N + 15) / 16, 192, 0, stream>>>(
        (const uint4*)T1h, (const uint4*)Hh, T2h, offs, adjw, dinv, N);

    // Layer 1: 96 -> 96 (fp16 A), APPNP x2, l2norm*1.5
    k_gemm_mfma<96, 96, 1><<<gblk, 256, 0, stream>>>(T2h, WT1, b1, Hh, N, 1.8f);
    k_prop_h<96, 16, 0, 0><<<(N + 15) / 16, 192, 0, stream>>>(
        (const uint4*)Hh, (const uint4*)Hh, T1h, offs, adjw, dinv, N);
    k_prop_h<96, 16, 0, 0><<<(N + 15) / 16, 192, 0, stream>>>(
        (const uint4*)T1h, (const uint4*)Hh, T2h, offs, adjw, dinv, N);
    k_l2norm_h96<<<(N + 3) / 4, 256, 0, stream>>>((uint*)T2h, N, 1.5f);

    // Layer 2: 96 -> 64 (fp16 A), APPNP x2, fp32 output
    k_gemm_mfma<96, 64, 1><<<gblk, 256, 0, stream>>>(T2h, WTx, bx, Hh, N, 1.8f);
    k_prop_h<64, 32, 0, 0><<<(N + 31) / 32, 256, 0, stream>>>(
        (const uint4*)Hh, (const uint4*)Hh, T1h, offs, adjw, dinv, N);
    k_prop_h<64, 32, 0, 1><<<(N + 31) / 32, 256, 0, stream>>>(
        (const uint4*)T1h, (const uint4*)Hh, out, offs, adjw, dinv, N);
}

// Round 3
// 291.463 us; speedup vs baseline: 1.7601x; 1.1913x over previous
//
#include <hip/hip_runtime.h>
#include <hip/hip_fp16.h>
#include <math.h>

#define BETA_C 0.85f   // 1 - alpha
#define ALF_C  0.15f   // alpha

typedef _Float16 f16x8 __attribute__((ext_vector_type(8)));
typedef float f32x4 __attribute__((ext_vector_type(4)));

// ---------------- preprocessing kernels ----------------

__global__ void k_count(const int* __restrict__ col, int* __restrict__ cnt, int E) {
    int stride = gridDim.x * blockDim.x;
    for (int e = blockIdx.x * blockDim.x + threadIdx.x; e < E; e += stride)
        atomicAdd(&cnt[col[e]], 1);
}

// dinv2[i] = (rsqrt(deg), 0.15*sqrt(deg)), deg = cnt+1 (self loop)
__global__ void k_dinv(const int* __restrict__ cnt, float2* __restrict__ dinv2, int n) {
    int i = blockIdx.x * blockDim.x + threadIdx.x;
    if (i < n) {
        float degf = (float)cnt[i] + 1.0f;
        dinv2[i] = make_float2(rsqrtf(degf), ALF_C * sqrtf(degf));
    }
}

__global__ void k_scan1(const int* __restrict__ cnt, int* __restrict__ aux, int n) {
    __shared__ int sm[4];
    int t = threadIdx.x;
    int base = blockIdx.x * 1024 + t * 4;
    int s = 0;
#pragma unroll
    for (int i = 0; i < 4; ++i) { int idx = base + i; if (idx < n) s += cnt[idx]; }
    for (int m = 1; m < 64; m <<= 1) s += __shfl_xor(s, m, 64);
    if ((t & 63) == 0) sm[t >> 6] = s;
    __syncthreads();
    if (t == 0) aux[blockIdx.x] = sm[0] + sm[1] + sm[2] + sm[3];
}

__global__ void k_scan2(int* __restrict__ aux, int nb) {
    if (threadIdx.x == 0 && blockIdx.x == 0) {
        int run = 0;
        for (int i = 0; i < nb; ++i) { int v = aux[i]; aux[i] = run; run += v; }
    }
}

__global__ void k_scan3(const int* __restrict__ cnt, const int* __restrict__ aux,
                        int* __restrict__ offs, int n, int total) {
    __shared__ int tsum[256];
    int t = threadIdx.x;
    int base = blockIdx.x * 1024 + t * 4;
    int v[4]; int s = 0;
#pragma unroll
    for (int i = 0; i < 4; ++i) { v[i] = (base + i < n) ? cnt[base + i] : 0; s += v[i]; }
    tsum[t] = s;
    __syncthreads();
    int run = s;
    for (int m = 1; m < 256; m <<= 1) {
        int add = (t >= m) ? tsum[t - m] : 0;
        __syncthreads();
        run += add;
        tsum[t] = run;
        __syncthreads();
    }
    int pre = aux[blockIdx.x] + (run - s);
#pragma unroll
    for (int i = 0; i < 4; ++i) {
        int idx = base + i;
        if (idx < n) { offs[idx] = pre; pre += v[i]; }
    }
    if (blockIdx.x == 0 && t == 0) offs[n] = total;
}

// CSR fill: adjacency only (weights are separable -> not stored)
__global__ void k_fill(const int* __restrict__ row, const int* __restrict__ col,
                       const int* __restrict__ offs, int* __restrict__ cur,
                       int* __restrict__ adj, int E) {
    int stride = gridDim.x * blockDim.x;
    for (int e = blockIdx.x * blockDim.x + threadIdx.x; e < E; e += stride) {
        int c = col[e];
        int p = atomicAdd(&cur[c], 1);
        adj[offs[c] + p] = row[e];
    }
}

// All three W[FI][FO] fp32 -> WT[FO][FI] fp16, one launch
__global__ void k_prepw_all(const float* __restrict__ W0, const float* __restrict__ W1,
                            const float* __restrict__ Wx, ushort* __restrict__ WT0,
                            ushort* __restrict__ WT1, ushort* __restrict__ WTx) {
    int idx = blockIdx.x * blockDim.x + threadIdx.x;
    const int S0 = 96 * 256, S1 = 96 * 96, S2 = 64 * 96;
    const float* W; ushort* WT; int FI, FO, li;
    if (idx < S0)            { W = W0; WT = WT0; FI = 256; FO = 96; li = idx; }
    else if (idx < S0 + S1)  { W = W1; WT = WT1; FI = 96;  FO = 96; li = idx - S0; }
    else if (idx < S0+S1+S2) { W = Wx; WT = WTx; FI = 96;  FO = 64; li = idx - S0 - S1; }
    else return;
    int nrow = li / FI, k = li % FI;
    _Float16 hv = (_Float16)W[(size_t)k * FO + nrow];
    WT[li] = *(ushort*)&hv;
}

// ---------------- MFMA fp16 GEMM + bias + l2norm*scale*dinv -> y-space fp16 ---
template<int FI, int FO, int ASRC_F16>
__global__ __launch_bounds__(256) void k_gemm_mfma(
        const void* __restrict__ Xv, const ushort* __restrict__ WT,
        const float* __restrict__ Bias, const float2* __restrict__ dinv2,
        ushort* __restrict__ H, int n, float scale) {
    constexpr int NT = FO / 16;
    constexpr int CPR = FI / 8;
    __shared__ ushort sA[64 * FI];
    __shared__ ushort sW[FO * FI];
    const int tid = threadIdx.x;
    const int rb = blockIdx.x * 64;

    {
        constexpr int TOT = FO * CPR;
#pragma unroll
        for (int idx = tid; idx < TOT; idx += 256) {
            int nrow = idx / CPR, c = idx % CPR;
            uint4 v = *(((const uint4*)WT) + (size_t)nrow * CPR + c);
            int byte = ((nrow * FI + c * 8) * 2) ^ ((nrow & 7) << 4);
            *(uint4*)((char*)sW + byte) = v;
        }
    }
    {
        constexpr int TOT = 64 * CPR;
#pragma unroll
        for (int idx = tid; idx < TOT; idx += 256) {
            int r = idx / CPR, c = idx % CPR;
            int gr = rb + r;
            uint4 v = make_uint4(0u, 0u, 0u, 0u);
            if (ASRC_F16) {
                if (gr < n) v = *(((const uint4*)Xv) + (size_t)gr * CPR + c);
            } else {
                if (gr < n) {
                    const float4* Xp = (const float4*)Xv;
                    float4 f0 = Xp[(size_t)gr * (FI / 4) + c * 2];
                    float4 f1 = Xp[(size_t)gr * (FI / 4) + c * 2 + 1];
                    _Float16 hv[8] = {(_Float16)f0.x, (_Float16)f0.y, (_Float16)f0.z,
                                      (_Float16)f0.w, (_Float16)f1.x, (_Float16)f1.y,
                                      (_Float16)f1.z, (_Float16)f1.w};
                    v = *(uint4*)hv;
                }
            }
            int byte = ((r * FI + c * 8) * 2) ^ ((r & 7) << 4);
            *(uint4*)((char*)sA + byte) = v;
        }
    }
    __syncthreads();

    const int lane = tid & 63;
    const int wave = tid >> 6;
    const int lcol = lane & 15;
    const int lk = lane >> 4;

    f32x4 acc[NT];
#pragma unroll
    for (int t = 0; t < NT; ++t) acc[t] = (f32x4){0.f, 0.f, 0.f, 0.f};

    const int arow = wave * 16 + lcol;
    char* sAb = (char*)sA;
    char* sWb = (char*)sW;
#pragma unroll
    for (int s = 0; s < FI / 32; ++s) {
        int abyte = ((arow * FI + s * 32 + lk * 8) * 2) ^ ((arow & 7) << 4);
        f16x8 af = *(f16x8*)(sAb + abyte);
#pragma unroll
        for (int t = 0; t < NT; ++t) {
            int nrow = t * 16 + lcol;
            int bbyte = ((nrow * FI + s * 32 + lk * 8) * 2) ^ ((nrow & 7) << 4);
            f16x8 bf = *(f16x8*)(sWb + bbyte);
            acc[t] = __builtin_amdgcn_mfma_f32_16x16x32_f16(af, bf, acc[t], 0, 0, 0);
        }
    }

    float bv[NT];
#pragma unroll
    for (int t = 0; t < NT; ++t) bv[t] = Bias[t * 16 + lcol];
    float ss[4] = {0.f, 0.f, 0.f, 0.f};
#pragma unroll
    for (int t = 0; t < NT; ++t)
#pragma unroll
        for (int r = 0; r < 4; ++r) {
            acc[t][r] += bv[t];
            ss[r] += acc[t][r] * acc[t][r];
        }
    for (int m = 1; m < 16; m <<= 1) {
#pragma unroll
        for (int r = 0; r < 4; ++r) ss[r] += __shfl_xor(ss[r], m, 64);
    }
#pragma unroll
    for (int r = 0; r < 4; ++r) {
        int grow = rb + wave * 16 + lk * 4 + r;
        if (grow < n) {
            float sc = scale * dinv2[grow].x / fmaxf(sqrtf(ss[r]), 1e-12f);
#pragma unroll
            for (int t = 0; t < NT; ++t) {
                _Float16 hv = (_Float16)(acc[t][r] * sc);
                H[(size_t)grow * FO + t * 16 + lcol] = *(ushort*)&hv;
            }
        }
    }
}

// ---------------- APPNP propagation (unweighted gather in y-space) -----------
__device__ inline void unpack8(uint4 v, float* f) {
    union { uint4 u; _Float16 h[8]; } U; U.u = v;
#pragma unroll
    for (int i = 0; i < 8; ++i) f[i] = (float)U.h[i];
}

template<int C8>
__device__ inline void gather_sum(const uint4* __restrict__ in,
                                  const int* __restrict__ adj,
                                  int e, int end, int j, float acc[8]) {
    for (; e + 4 <= end; e += 4) {
        int r0 = adj[e], r1 = adj[e + 1], r2 = adj[e + 2], r3 = adj[e + 3];
        uint4 v0 = in[(size_t)r0 * C8 + j];
        uint4 v1 = in[(size_t)r1 * C8 + j];
        uint4 v2 = in[(size_t)r2 * C8 + j];
        uint4 v3 = in[(size_t)r3 * C8 + j];
        float f0[8], f1[8], f2[8], f3[8];
        unpack8(v0, f0); unpack8(v1, f1); unpack8(v2, f2); unpack8(v3, f3);
#pragma unroll
        for (int i = 0; i < 8; ++i) acc[i] += (f0[i] + f1[i]) + (f2[i] + f3[i]);
    }
    for (; e < end; ++e) {
        uint4 v = in[(size_t)adj[e] * C8 + j];
        float f[8]; unpack8(v, f);
#pragma unroll
        for (int i = 0; i < 8; ++i) acc[i] += f[i];
    }
}

// prop step 1 (y -> y): y1 = 0.85 d^2 (gather + y0) + 0.15 y0
template<int FO, int NPB>
__global__ __launch_bounds__(NPB * FO / 8) void k_prop1(
        const uint4* __restrict__ y0, uint4* __restrict__ y1,
        const int* __restrict__ offs, const int* __restrict__ adj,
        const float2* __restrict__ dinv2, int n) {
    constexpr int C8 = FO / 8;
    int tid = threadIdx.x;
    int j = tid % C8, cl = tid / C8;
    int c = blockIdx.x * NPB + cl;
    if (c >= n) return;
    float d = dinv2[c].x;
    float a = BETA_C * d * d;
    float b = a + ALF_C;
    float acc[8] = {0, 0, 0, 0, 0, 0, 0, 0};
    gather_sum<C8>(y0, adj, offs[c], offs[c + 1], j, acc);
    float sf[8];
    unpack8(y0[(size_t)c * C8 + j], sf);
    _Float16 hv[8];
#pragma unroll
    for (int i = 0; i < 8; ++i) hv[i] = (_Float16)(a * acc[i] + b * sf[i]);
    y1[(size_t)c * C8 + j] = *(uint4*)hv;
}

// prop step 2 (y -> x): x = 0.85 d (gather + y1) + 0.15 sqrt(deg) y0  [+relu]
template<int FO, int NPB, int ACT, int OUTF32>
__global__ __launch_bounds__(NPB * FO / 8) void k_prop2(
        const uint4* __restrict__ y1, const uint4* __restrict__ y0,
        void* __restrict__ out, const int* __restrict__ offs,
        const int* __restrict__ adj, const float2* __restrict__ dinv2, int n) {
    constexpr int C8 = FO / 8;
    int tid = threadIdx.x;
    int j = tid % C8, cl = tid / C8;
    int c = blockIdx.x * NPB + cl;
    if (c >= n) return;
    float2 dv = dinv2[c];
    float a = BETA_C * dv.x;       // 0.85 * dinv
    float t = dv.y;                // 0.15 * sqrt(deg)
    float acc[8] = {0, 0, 0, 0, 0, 0, 0, 0};
    gather_sum<C8>(y1, adj, offs[c], offs[c + 1], j, acc);
    float sf[8], tf[8];
    unpack8(y1[(size_t)c * C8 + j], sf);
    unpack8(y0[(size_t)c * C8 + j], tf);
    float res[8];
#pragma unroll
    for (int i = 0; i < 8; ++i) {
        res[i] = a * (acc[i] + sf[i]) + t * tf[i];
        if (ACT) res[i] = fmaxf(res[i], 0.f);
    }
    if (OUTF32) {
        float4* op = (float4*)out;
        op[(size_t)c * (FO / 4) + j * 2]     = make_float4(res[0], res[1], res[2], res[3]);
        op[(size_t)c * (FO / 4) + j * 2 + 1] = make_float4(res[4], res[5], res[6], res[7]);
    } else {
        _Float16 hv[8];
#pragma unroll
        for (int i = 0; i < 8; ++i) hv[i] = (_Float16)res[i];
        ((uint4*)out)[(size_t)c * C8 + j] = *(uint4*)hv;
    }
}

// ---------------- row l2norm * scale, fp16 in-place, FO=96 ----------------
__global__ void k_l2norm_h96(uint* __restrict__ x, int n, float scale) {
    int lane = threadIdx.x & 63, wave = threadIdx.x >> 6;
    int r = blockIdx.x * 4 + wave;
    if (r >= n) return;
    uint* p = x + (size_t)r * 48;
    float2 vf = make_float2(0.f, 0.f);
    if (lane < 48) {
        uint v = p[lane];
        union { uint u; _Float16 h[2]; } U; U.u = v;
        vf.x = (float)U.h[0]; vf.y = (float)U.h[1];
    }
    float ss = vf.x * vf.x + vf.y * vf.y;
    for (int m = 1; m < 64; m <<= 1) ss += __shfl_xor(ss, m, 64);
    float sc = scale / fmaxf(sqrtf(ss), 1e-12f);
    if (lane < 48) {
        union { uint u; _Float16 h[2]; } U;
        U.h[0] = (_Float16)(vf.x * sc); U.h[1] = (_Float16)(vf.y * sc);
        p[lane] = U.u;
    }
}

// ---------------- host launcher ----------------
extern "C" void kernel_launch(void* const* d_in, const int* in_sizes, int n_in,
                              void* d_out, int out_size, void* d_ws, size_t ws_size,
                              hipStream_t stream) {
    const float* x  = (const float*)d_in[0];
    const int*   ei = (const int*)d_in[1];
    const float* W0 = (const float*)d_in[2];
    const float* b0 = (const float*)d_in[3];
    const float* W1 = (const float*)d_in[4];
    const float* b1 = (const float*)d_in[5];
    const float* Wx = (const float*)d_in[6];
    const float* bx = (const float*)d_in[7];
    float* out = (float*)d_out;

    const int N = in_sizes[0] / 256;
    const int E = in_sizes[1] / 2;
    const int* row = ei;
    const int* col = ei + E;

    char* ws = (char*)d_ws;
    size_t off = 0;
    auto alloc = [&](size_t bytes) -> char* {
        char* p = ws + off;
        off += (bytes + 255) & ~(size_t)255;
        return p;
    };
    int*    cnt   = (int*)alloc((size_t)N * 4);
    int*    cur   = (int*)alloc((size_t)N * 4);
    float2* dinv2 = (float2*)alloc((size_t)N * 8);
    int*    offs  = (int*)alloc((size_t)(N + 1) * 4);
    int*    aux   = (int*)alloc(256 * 4);
    int*    adj   = (int*)alloc((size_t)E * 4);
    ushort* WT0   = (ushort*)alloc((size_t)96 * 256 * 2);
    ushort* WT1   = (ushort*)alloc((size_t)96 * 96 * 2);
    ushort* WTx   = (ushort*)alloc((size_t)64 * 96 * 2);
    ushort* Hh    = (ushort*)alloc((size_t)N * 96 * 2);
    ushort* T1h   = (ushort*)alloc((size_t)N * 96 * 2);
    ushort* T2h   = (ushort*)alloc((size_t)N * 96 * 2);
    (void)ws_size; (void)n_in; (void)out_size;

    int nblkN = (N + 255) / 256;
    int nscan = (N + 1023) / 1024;
    hipMemsetAsync(cnt, 0, (size_t)N * 4, stream);
    hipMemsetAsync(cur, 0, (size_t)N * 4, stream);
    k_count<<<1024, 256, 0, stream>>>(col, cnt, E);
    k_dinv<<<nblkN, 256, 0, stream>>>(cnt, dinv2, N);
    k_scan1<<<nscan, 256, 0, stream>>>(cnt, aux, N);
    k_scan2<<<1, 64, 0, stream>>>(aux, nscan);
    k_scan3<<<nscan, 256, 0, stream>>>(cnt, aux, offs, N, E);
    k_fill<<<1024, 256, 0, stream>>>(row, col, offs, cur, adj, E);
    {
        int tot = 96 * 256 + 96 * 96 + 64 * 96;
        k_prepw_all<<<(tot + 255) / 256, 256, 0, stream>>>(W0, W1, Wx, WT0, WT1, WTx);
    }

    int gblk = (N + 63) / 64;
    // Layer 0: 256 -> 96, APPNP x2 (relu fused into prop2)
    k_gemm_mfma<256, 96, 0><<<gblk, 256, 0, stream>>>(x, WT0, b0, dinv2, Hh, N, 1.8f);
    k_prop1<96, 16><<<(N + 15) / 16, 192, 0, stream>>>(
        (const uint4*)Hh, (uint4*)T1h, offs, adj, dinv2, N);
    k_prop2<96, 16, 1, 0><<<(N + 15) / 16, 192, 0, stream>>>(
        (const uint4*)T1h, (const uint4*)Hh, T2h, offs, adj, dinv2, N);

    // Layer 1: 96 -> 96, APPNP x2, l2norm*1.5
    k_gemm_mfma<96, 96, 1><<<gblk, 256, 0, stream>>>(T2h, WT1, b1, dinv2, Hh, N, 1.8f);
    k_prop1<96, 16><<<(N + 15) / 16, 192, 0, stream>>>(
        (const uint4*)Hh, (uint4*)T1h, offs, adj, dinv2, N);
    k_prop2<96, 16, 0, 0><<<(N + 15) / 16, 192, 0, stream>>>(
        (const uint4*)T1h, (const uint4*)Hh, T2h, offs, adj, dinv2, N);
    k_l2norm_h96<<<(N + 3) / 4, 256, 0, stream>>>((uint*)T2h, N, 1.5f);

    // Layer 2: 96 -> 64, APPNP x2, fp32 output
    k_gemm_mfma<96, 64, 1><<<gblk, 256, 0, stream>>>(T2h, WTx, bx, dinv2, Hh, N, 1.8f);
    k_prop1<64, 32><<<(N + 31) / 32, 256, 0, stream>>>(
        (const uint4*)Hh, (uint4*)T1h, offs, adj, dinv2, N);
    k_prop2<64, 32, 0, 1><<<(N + 31) / 32, 256, 0, stream>>>(
        (const uint4*)T1h, (const uint4*)Hh, out, offs, adj, dinv2, N);
}